// Round 3
// baseline (355.075 us; speedup 1.0000x reference)
//
#include <hip/hip_runtime.h>
#include <math.h>

// Problem constants (B=16, C=2, H=1024, W=1024)
#define HW   (1024 * 1024)          // H*W = 1M (power of two)
#define NPIX (16 * HW)              // B*H*W = 16,777,216
#define NGRP (NPIX / 4)             // float4 groups over pixel space = 4,194,304

constexpr int THREADS   = 256;
constexpr int NBLK      = 2048;                    // G11: ~8 blocks/CU, grid-stride
constexpr int TOTALTHR  = NBLK * THREADS;          // 524,288 threads
constexpr int ITERS     = NGRP / TOTALTHR;         // 8 float4-groups per thread
static_assert(ITERS * TOTALTHR == NGRP, "exact tiling");

__device__ __forceinline__ float fast_sigmoid(float x) {
    return __builtin_amdgcn_rcpf(1.0f + __expf(-x));
}

__device__ __forceinline__ float elem_loss(float x0, float x1, float t0, float t1) {
    float p0 = fast_sigmoid(x0);
    float p1 = fast_sigmoid(x1);
    // p0,p1 in (0,1): e^p in (1,e), no stabilization needed
    float lse = __logf(__expf(p0) + __expf(p1));
    return (t0 + t1) * lse - (t0 * p0 + t1 * p1);
}

// Grid-stride streaming kernel: 2048 blocks, 8 float4-groups/thread.
// Reduction machinery (12 shuffles + LDS + 2 barriers) amortized over
// 768 B/thread instead of 96 B/thread; unroll-2 keeps two iterations' loads
// (12 float4s) in flight for MLP on top of 16 waves/CU TLP.
__global__ __launch_bounds__(THREADS, 4) void xy_loss_main(
    const float* __restrict__ mask,   // [B,1,H,W]
    const float* __restrict__ scale,  // [B,1,H,W]
    const float* __restrict__ pred,   // [B,2,H,W]
    const float* __restrict__ truth,  // [B,2,H,W]
    float* __restrict__ ws)           // [0..NBLK): S1 parts, [NBLK..2*NBLK): S2 parts
{
    float s1 = 0.0f, s2 = 0.0f;
    int g = blockIdx.x * THREADS + threadIdx.x;

    #pragma unroll 2
    for (int k = 0; k < ITERS; ++k, g += TOTALTHR) {
        const int i    = g << 2;                 // flat pixel index (b*HW + hw)
        const int base = i + (i & ~(HW - 1));    // b*2*HW + hw

        const float4 x0 = *(const float4*)(pred  + base);
        const float4 x1 = *(const float4*)(pred  + base + HW);
        const float4 t0 = *(const float4*)(truth + base);
        const float4 t1 = *(const float4*)(truth + base + HW);
        const float4 mk = *(const float4*)(mask  + i);
        const float4 sc = *(const float4*)(scale + i);

        s1 += elem_loss(x0.x, x1.x, t0.x, t1.x)
            + elem_loss(x0.y, x1.y, t0.y, t1.y)
            + elem_loss(x0.z, x1.z, t0.z, t1.z)
            + elem_loss(x0.w, x1.w, t0.w, t1.w);
        s2 += mk.x * sc.x + mk.y * sc.y + mk.z * sc.z + mk.w * sc.w;
    }

    // wave64 shuffle reduction
    #pragma unroll
    for (int off = 32; off > 0; off >>= 1) {
        s1 += __shfl_down(s1, off, 64);
        s2 += __shfl_down(s2, off, 64);
    }

    __shared__ float ls1[4], ls2[4];
    const int lane = threadIdx.x & 63;
    const int wv   = threadIdx.x >> 6;
    if (lane == 0) { ls1[wv] = s1; ls2[wv] = s2; }
    __syncthreads();

    if (threadIdx.x == 0) {
        ws[blockIdx.x]        = ls1[0] + ls1[1] + ls1[2] + ls1[3];
        ws[NBLK + blockIdx.x] = ls2[0] + ls2[1] + ls2[2] + ls2[3];
    }
}

__global__ __launch_bounds__(1024) void xy_finalize(
    const float* __restrict__ ws, float* __restrict__ out)
{
    const int tid = threadIdx.x;
    // NBLK = 2048 partials per array, 1024 threads -> 2 each
    float a = ws[tid]        + ws[tid + 1024];
    float b = ws[NBLK + tid] + ws[NBLK + tid + 1024];

    #pragma unroll
    for (int off = 32; off > 0; off >>= 1) {
        a += __shfl_down(a, off, 64);
        b += __shfl_down(b, off, 64);
    }
    __shared__ float la[16], lb[16];
    const int lane = tid & 63;
    const int wv   = tid >> 6;
    if (lane == 0) { la[wv] = a; lb[wv] = b; }
    __syncthreads();
    if (tid == 0) {
        float s1 = 0.0f, s2 = 0.0f;
        #pragma unroll
        for (int w = 0; w < 16; ++w) { s1 += la[w]; s2 += lb[w]; }
        out[0] = s1 * s2 * (1.0f / (float)NPIX);
    }
}

extern "C" void kernel_launch(void* const* d_in, const int* in_sizes, int n_in,
                              void* d_out, int out_size, void* d_ws, size_t ws_size,
                              hipStream_t stream) {
    const float* mask  = (const float*)d_in[0];  // object_mask    [16,1,1024,1024]
    const float* scale = (const float*)d_in[1];  // box_loss_scale [16,1,1024,1024]
    const float* pred  = (const float*)d_in[2];  // predict_xy     [16,2,1024,1024]
    const float* truth = (const float*)d_in[3];  // true_xy        [16,2,1024,1024]
    float* out = (float*)d_out;
    float* ws  = (float*)d_ws;                   // 2*NBLK floats = 16 KB of partials

    xy_loss_main<<<NBLK, THREADS, 0, stream>>>(mask, scale, pred, truth, ws);
    xy_finalize<<<1, 1024, 0, stream>>>(ws, out);
}